// Round 3
// baseline (666.278 us; speedup 1.0000x reference)
//
#include <hip/hip_runtime.h>
#include <cstdint>
#include <cstddef>

#define BB 64
#define NN 1024
#define DD 128

typedef short    bf16x8 __attribute__((ext_vector_type(8)));
typedef _Float16 f16x8  __attribute__((ext_vector_type(8)));
typedef float    f32x4  __attribute__((ext_vector_type(4)));

__device__ __forceinline__ unsigned short f2bf(float f) {
  union { float f; unsigned u; } v; v.f = f;
  unsigned r = v.u + 0x7FFFu + ((v.u >> 16) & 1u);
  return (unsigned short)(r >> 16);
}
__device__ __forceinline__ unsigned short f2h(float f) {
  union { _Float16 h; unsigned short u; } v; v.h = (_Float16)f;
  return v.u;
}
__device__ __forceinline__ float fast_tanh(float x) {
  x = fminf(15.0f, fmaxf(-15.0f, x));
  float e = __expf(2.0f * x);
  return (e - 1.0f) / (e + 1.0f);
}

// ---------------------------------------------------------------------------
// Kernel 1: q = tanh(x@Wq^T+bq) (fp16), k = tanh(x@Wk^T+bk) (fp16),
//           vT = tanh(x@Wv^T+bv) transposed (bf16, [b][h][n]).
// ---------------------------------------------------------------------------
__global__ __launch_bounds__(256, 2) void proj_kernel(
    const float* __restrict__ x,
    const float* __restrict__ Wq, const float* __restrict__ bq,
    const float* __restrict__ Wk, const float* __restrict__ bk,
    const float* __restrict__ Wv, const float* __restrict__ bv,
    unsigned short* __restrict__ qg,   // fp16 [B][N][D]
    unsigned short* __restrict__ kg,   // fp16 [B][N][D]
    unsigned short* __restrict__ vtg)  // bf16 [B][D][N]
{
  __shared__ unsigned short wlds[128 * 136];

  const int tid  = threadIdx.x;
  const int lane = tid & 63;
  const int wave = tid >> 6;
  const int quad = lane >> 4;
  const int mr   = lane & 15;
  const int m0   = blockIdx.x * 128;
  const int batch = m0 >> 10;
  const int n0    = m0 & 1023;

  bf16x8 xa[2][4];
#pragma unroll
  for (int mt = 0; mt < 2; ++mt) {
    const float* xr = x + (size_t)(m0 + wave * 32 + mt * 16 + mr) * DD + quad * 8;
#pragma unroll
    for (int ks = 0; ks < 4; ++ks) {
      const float4* xp = (const float4*)(xr + ks * 32);
      float4 f0 = xp[0], f1 = xp[1];
      bf16x8 f;
      f[0] = (short)f2bf(f0.x); f[1] = (short)f2bf(f0.y);
      f[2] = (short)f2bf(f0.z); f[3] = (short)f2bf(f0.w);
      f[4] = (short)f2bf(f1.x); f[5] = (short)f2bf(f1.y);
      f[6] = (short)f2bf(f1.z); f[7] = (short)f2bf(f1.w);
      xa[mt][ks] = f;
    }
  }

  const float* Wp[3] = {Wq, Wk, Wv};
  const float* bp[3] = {bq, bk, bv};

  for (int w = 0; w < 3; ++w) {
    __syncthreads();
    {
      const int row = tid >> 1, half = tid & 1;
      const float* src = Wp[w] + row * 128 + half * 64;
      unsigned short* dst = wlds + row * 136 + half * 64;
#pragma unroll
      for (int c = 0; c < 64; c += 8) {
        const float4* sp = (const float4*)(src + c);
        float4 f0 = sp[0], f1 = sp[1];
        unsigned short tmp[8];
        tmp[0] = f2bf(f0.x); tmp[1] = f2bf(f0.y); tmp[2] = f2bf(f0.z); tmp[3] = f2bf(f0.w);
        tmp[4] = f2bf(f1.x); tmp[5] = f2bf(f1.y); tmp[6] = f2bf(f1.z); tmp[7] = f2bf(f1.w);
        uint4 pk; __builtin_memcpy(&pk, tmp, 16);
        *(uint4*)(dst + c) = pk;
      }
    }
    __syncthreads();

    f32x4 z = {0.f, 0.f, 0.f, 0.f};
    f32x4 acc[2][8];
#pragma unroll
    for (int mt = 0; mt < 2; ++mt)
#pragma unroll
      for (int nt = 0; nt < 8; ++nt) acc[mt][nt] = z;

#pragma unroll
    for (int ks = 0; ks < 4; ++ks) {
#pragma unroll
      for (int nt = 0; nt < 8; ++nt) {
        bf16x8 bfr = *(const bf16x8*)(wlds + (nt * 16 + mr) * 136 + ks * 32 + quad * 8);
        acc[0][nt] = __builtin_amdgcn_mfma_f32_16x16x32_bf16(xa[0][ks], bfr, acc[0][nt], 0, 0, 0);
        acc[1][nt] = __builtin_amdgcn_mfma_f32_16x16x32_bf16(xa[1][ks], bfr, acc[1][nt], 0, 0, 0);
      }
    }

    if (w < 2) {
      unsigned short* outg = (w == 0) ? qg : kg;
#pragma unroll
      for (int mt = 0; mt < 2; ++mt) {
        const int rowbase = m0 + wave * 32 + mt * 16 + quad * 4;
#pragma unroll
        for (int nt = 0; nt < 8; ++nt) {
          float bb = bp[w][nt * 16 + mr];
#pragma unroll
          for (int r = 0; r < 4; ++r) {
            float t = fast_tanh(acc[mt][nt][r] + bb);
            outg[(size_t)(rowbase + r) * DD + nt * 16 + mr] = f2h(t);
          }
        }
      }
    } else {
      __syncthreads();
#pragma unroll
      for (int mt = 0; mt < 2; ++mt) {
        const int ib = wave * 32 + mt * 16 + quad * 4;
#pragma unroll
        for (int nt = 0; nt < 8; ++nt) {
          float bb = bp[2][nt * 16 + mr];
#pragma unroll
          for (int r = 0; r < 4; ++r) {
            float t = fast_tanh(acc[mt][nt][r] + bb);
            wlds[(nt * 16 + mr) * 136 + ib + r] = f2bf(t);
          }
        }
      }
      __syncthreads();
      const int h = tid >> 1, half = tid & 1;
      const unsigned short* src = wlds + h * 136 + half * 64;
      unsigned short* dst = vtg + (size_t)(batch * 128 + h) * NN + n0 + half * 64;
#pragma unroll
      for (int c = 0; c < 64; c += 8)
        *(uint4*)(dst + c) = *(const uint4*)(src + c);
    }
  }
}

// ---------------------------------------------------------------------------
// Kernel 2: flash-style masked attention.
// Block = 64 q-rows (4 waves x 16 rows), j-tiles of 64.
// plds aliases klds (disjoint phases). Mask applied at PV A-frag read via
// bit-packed int4 loads prefetched one tile ahead. Row-sum via VALU.
// launch_bounds(256,2): R1's (256,4) squeezed VGPR to 64 -> 520 MB scratch
// spill traffic (WRITE_SIZE 557 MB). Let the allocator keep ~115 live regs;
// LDS 35840 B still permits 4 blocks/CU if VGPR <= 128.
// ---------------------------------------------------------------------------
__global__ __launch_bounds__(256, 2) void attn_kernel(
    const unsigned short* __restrict__ qg,
    const unsigned short* __restrict__ kg,
    const unsigned short* __restrict__ vtg,
    const int* __restrict__ mask,
    float* __restrict__ out)
{
  extern __shared__ unsigned short lds[];
  unsigned short* klds = lds;          // [64][136] fp16 during S phase
  unsigned short* plds = lds;          // [64][72]  bf16 during PV phase (alias)
  unsigned short* vlds = lds + 8704;   // [128][72] bf16

  const int tid  = threadIdx.x;
  const int lane = tid & 63;
  const int wave = tid >> 6;
  const int quad = lane >> 4;
  const int mr   = lane & 15;

  const int bx    = blockIdx.x;
  const int batch = ((bx >> 7) << 3) | (bx & 7);   // same-batch blocks -> same XCD
  const int i0    = ((bx >> 3) & 15) * 64;

  const unsigned short* kgb = kg  + (size_t)batch * NN * DD;
  const unsigned short* vtb = vtg + (size_t)batch * DD * NN;
  const int* mrow = mask + ((size_t)batch << 20) + (size_t)(i0 + wave * 16 + mr) * NN;

  // Q A-frags (fp16): row = i0 + wave*16 + mr, k = ks*32 + quad*8 + e
  f16x8 qa[4];
#pragma unroll
  for (int ks = 0; ks < 4; ++ks)
    qa[ks] = *(const f16x8*)(qg +
        ((size_t)batch * NN + i0 + wave * 16 + mr) * DD + ks * 32 + quad * 8);

  f32x4 z = {0.f, 0.f, 0.f, 0.f};
  f32x4 o[8];
#pragma unroll
  for (int nt = 0; nt < 8; ++nt) o[nt] = z;
  float rowsum = 0.0f;

  const int kj = tid >> 2, ksg = (tid & 3) * 32;   // K stage: 64B/thread
  const int vh = tid >> 1, vsg = (tid & 1) * 32;   // VT stage: 64B/thread
  const unsigned short* ksrc = kgb + ksg;
  const unsigned short* vsrc = vtb + (size_t)vh * NN + vsg;

  // mask prefetch for tile 0
  int4 mreg[4];
  mreg[0] = *(const int4*)(mrow + quad * 8);
  mreg[1] = *(const int4*)(mrow + quad * 8 + 4);
  mreg[2] = *(const int4*)(mrow + 32 + quad * 8);
  mreg[3] = *(const int4*)(mrow + 32 + quad * 8 + 4);

  for (int t = 0; t < 16; ++t) {
    const int j0 = t * 64;

    // K/V staging loads for tile t (in flight across B1)
    uint4 kreg[4], vreg[4];
    {
      const uint4* s1 = (const uint4*)(ksrc + (size_t)(j0 + kj) * DD);
      const uint4* s2 = (const uint4*)(vsrc + j0);
#pragma unroll
      for (int c = 0; c < 4; ++c) { kreg[c] = s1[c]; vreg[c] = s2[c]; }
    }

    // pack mask bits for tile t; bit (ks2*8 + e) = mask[row][j0 + ks2*32 + quad*8 + e]
    unsigned mb = 0;
#pragma unroll
    for (int i = 0; i < 4; ++i) {
      mb |= (unsigned)(mreg[i].x & 1) << (i * 4 + 0);
      mb |= (unsigned)(mreg[i].y & 1) << (i * 4 + 1);
      mb |= (unsigned)(mreg[i].z & 1) << (i * 4 + 2);
      mb |= (unsigned)(mreg[i].w & 1) << (i * 4 + 3);
    }
    // prefetch mask for tile t+1 (hidden behind the whole iteration)
    {
      const int j0n = ((t + 1) & 15) * 64;
      mreg[0] = *(const int4*)(mrow + j0n + quad * 8);
      mreg[1] = *(const int4*)(mrow + j0n + quad * 8 + 4);
      mreg[2] = *(const int4*)(mrow + j0n + 32 + quad * 8);
      mreg[3] = *(const int4*)(mrow + j0n + 32 + quad * 8 + 4);
    }

    __syncthreads();  // B1: prev PV reads of plds/vlds done
    {
      uint4* d1 = (uint4*)(klds + kj * 136 + ksg);
      uint4* d2 = (uint4*)(vlds + vh * 72 + vsg);
#pragma unroll
      for (int c = 0; c < 4; ++c) d1[c] = kreg[c];
#pragma unroll
      for (int c = 0; c < 4; ++c) d2[c] = vreg[c];
    }
    __syncthreads();  // B2: staging visible

    // S = Q @ K^T (fp16 MFMA); per-wave tile 16 x 64
    f32x4 s[4];
#pragma unroll
    for (int nt = 0; nt < 4; ++nt) s[nt] = z;
#pragma unroll
    for (int ks = 0; ks < 4; ++ks) {
#pragma unroll
      for (int nt = 0; nt < 4; ++nt) {
        f16x8 kb = *(const f16x8*)(klds + (nt * 16 + mr) * 136 + ks * 32 + quad * 8);
        s[nt] = __builtin_amdgcn_mfma_f32_16x16x32_f16(qa[ks], kb, s[nt], 0, 0, 0);
      }
    }
    __syncthreads();  // B3: klds reads done, region becomes plds

    // P = exp(S) -> bf16 -> plds (unmasked; mask applied at A-frag read)
#pragma unroll
    for (int nt = 0; nt < 4; ++nt) {
#pragma unroll
      for (int r = 0; r < 4; ++r)
        plds[(wave * 16 + quad * 4 + r) * 72 + nt * 16 + mr] = f2bf(__expf(s[nt][r]));
    }
    __syncthreads();  // B4: P visible

    // O += P_masked @ V; row-sum accumulated in-lane from the same bf16 values
#pragma unroll
    for (int ks2 = 0; ks2 < 2; ++ks2) {
      bf16x8 pa = *(const bf16x8*)(plds + (wave * 16 + mr) * 72 + ks2 * 32 + quad * 8);
      bf16x8 pm;
#pragma unroll
      for (int e = 0; e < 8; ++e) {
        unsigned bit = (mb >> (ks2 * 8 + e)) & 1u;
        short pv = bit ? pa[e] : (short)0;
        pm[e] = pv;
        union { unsigned u; float f; } cv;
        cv.u = ((unsigned)(unsigned short)pv) << 16;
        rowsum += cv.f;
      }
#pragma unroll
      for (int nt = 0; nt < 8; ++nt) {
        bf16x8 vb = *(const bf16x8*)(vlds + (nt * 16 + mr) * 72 + ks2 * 32 + quad * 8);
        o[nt] = __builtin_amdgcn_mfma_f32_16x16x32_bf16(pm, vb, o[nt], 0, 0, 0);
      }
    }
  }

  // reduce row-sum across the 4 quads
  rowsum += __shfl_xor(rowsum, 16, 64);
  rowsum += __shfl_xor(rowsum, 32, 64);

  float* ob = out + ((size_t)batch * NN + i0) * DD;
#pragma unroll
  for (int r = 0; r < 4; ++r) {
    float rs  = __shfl(rowsum, quad * 4 + r, 64);  // rs for row wave*16+quad*4+r
    float inv = 1.0f / rs;
    float* orow = ob + (size_t)(wave * 16 + quad * 4 + r) * DD + mr;
#pragma unroll
    for (int nt = 0; nt < 8; ++nt)
      orow[nt * 16] = o[nt][r] * inv;
  }
}

// ---------------------------------------------------------------------------
extern "C" void kernel_launch(void* const* d_in, const int* in_sizes, int n_in,
                              void* d_out, int out_size, void* d_ws, size_t ws_size,
                              hipStream_t stream) {
  (void)in_sizes; (void)n_in; (void)out_size; (void)ws_size;
  const float* x  = (const float*)d_in[0];
  const int* mask = (const int*)d_in[1];
  const float* Wv = (const float*)d_in[2];
  const float* bv = (const float*)d_in[3];
  const float* Wk = (const float*)d_in[4];
  const float* bk = (const float*)d_in[5];
  const float* Wq = (const float*)d_in[6];
  const float* bq = (const float*)d_in[7];
  float* out = (float*)d_out;

  unsigned short* qg  = (unsigned short*)d_ws;          // fp16 [B][N][D]
  unsigned short* kg  = qg + (size_t)BB * NN * DD;      // fp16 [B][N][D]
  unsigned short* vtg = kg + (size_t)BB * NN * DD;      // bf16 [B][D][N]

  proj_kernel<<<512, 256, 0, stream>>>(x, Wq, bq, Wk, bk, Wv, bv, qg, kg, vtg);
  attn_kernel<<<1024, 256, 35840, stream>>>(qg, kg, vtg, mask, out);
}

// Round 4
// 455.823 us; speedup vs baseline: 1.4617x; 1.4617x over previous
//
#include <hip/hip_runtime.h>
#include <cstdint>
#include <cstddef>

#define BB 64
#define NN 1024
#define DD 128

typedef short    bf16x8 __attribute__((ext_vector_type(8)));
typedef _Float16 f16x8  __attribute__((ext_vector_type(8)));
typedef float    f32x4  __attribute__((ext_vector_type(4)));

__device__ __forceinline__ unsigned short f2bf(float f) {
  union { float f; unsigned u; } v; v.f = f;
  unsigned r = v.u + 0x7FFFu + ((v.u >> 16) & 1u);
  return (unsigned short)(r >> 16);
}
__device__ __forceinline__ unsigned short f2h(float f) {
  union { _Float16 h; unsigned short u; } v; v.h = (_Float16)f;
  return v.u;
}
__device__ __forceinline__ float fast_tanh(float x) {
  x = fminf(15.0f, fmaxf(-15.0f, x));
  float e = __expf(2.0f * x);
  return (e - 1.0f) / (e + 1.0f);
}

// async global->LDS DMA, 16 B per lane (global_load_lds_dwordx4)
__device__ __forceinline__ void async_copy16(void* lptr, const void* gptr) {
  __builtin_amdgcn_global_load_lds(
      (const __attribute__((address_space(1))) unsigned int*)gptr,
      (__attribute__((address_space(3))) unsigned int*)lptr, 16, 0, 0);
}

// ---------------------------------------------------------------------------
// Kernel 1: q = tanh(x@Wq^T+bq) (fp16), k = tanh(x@Wk^T+bk) (fp16),
//           vT = tanh(x@Wv^T+bv) transposed (bf16, [b][h][n]).
// ---------------------------------------------------------------------------
__global__ __launch_bounds__(256, 2) void proj_kernel(
    const float* __restrict__ x,
    const float* __restrict__ Wq, const float* __restrict__ bq,
    const float* __restrict__ Wk, const float* __restrict__ bk,
    const float* __restrict__ Wv, const float* __restrict__ bv,
    unsigned short* __restrict__ qg,   // fp16 [B][N][D]
    unsigned short* __restrict__ kg,   // fp16 [B][N][D]
    unsigned short* __restrict__ vtg)  // bf16 [B][D][N]
{
  __shared__ unsigned short wlds[128 * 136];

  const int tid  = threadIdx.x;
  const int lane = tid & 63;
  const int wave = tid >> 6;
  const int quad = lane >> 4;
  const int mr   = lane & 15;
  const int m0   = blockIdx.x * 128;
  const int batch = m0 >> 10;
  const int n0    = m0 & 1023;

  bf16x8 xa[2][4];
#pragma unroll
  for (int mt = 0; mt < 2; ++mt) {
    const float* xr = x + (size_t)(m0 + wave * 32 + mt * 16 + mr) * DD + quad * 8;
#pragma unroll
    for (int ks = 0; ks < 4; ++ks) {
      const float4* xp = (const float4*)(xr + ks * 32);
      float4 f0 = xp[0], f1 = xp[1];
      bf16x8 f;
      f[0] = (short)f2bf(f0.x); f[1] = (short)f2bf(f0.y);
      f[2] = (short)f2bf(f0.z); f[3] = (short)f2bf(f0.w);
      f[4] = (short)f2bf(f1.x); f[5] = (short)f2bf(f1.y);
      f[6] = (short)f2bf(f1.z); f[7] = (short)f2bf(f1.w);
      xa[mt][ks] = f;
    }
  }

  const float* Wp[3] = {Wq, Wk, Wv};
  const float* bp[3] = {bq, bk, bv};

  for (int w = 0; w < 3; ++w) {
    __syncthreads();
    {
      const int row = tid >> 1, half = tid & 1;
      const float* src = Wp[w] + row * 128 + half * 64;
      unsigned short* dst = wlds + row * 136 + half * 64;
#pragma unroll
      for (int c = 0; c < 64; c += 8) {
        const float4* sp = (const float4*)(src + c);
        float4 f0 = sp[0], f1 = sp[1];
        unsigned short tmp[8];
        tmp[0] = f2bf(f0.x); tmp[1] = f2bf(f0.y); tmp[2] = f2bf(f0.z); tmp[3] = f2bf(f0.w);
        tmp[4] = f2bf(f1.x); tmp[5] = f2bf(f1.y); tmp[6] = f2bf(f1.z); tmp[7] = f2bf(f1.w);
        uint4 pk; __builtin_memcpy(&pk, tmp, 16);
        *(uint4*)(dst + c) = pk;
      }
    }
    __syncthreads();

    f32x4 z = {0.f, 0.f, 0.f, 0.f};
    f32x4 acc[2][8];
#pragma unroll
    for (int mt = 0; mt < 2; ++mt)
#pragma unroll
      for (int nt = 0; nt < 8; ++nt) acc[mt][nt] = z;

#pragma unroll
    for (int ks = 0; ks < 4; ++ks) {
#pragma unroll
      for (int nt = 0; nt < 8; ++nt) {
        bf16x8 bfr = *(const bf16x8*)(wlds + (nt * 16 + mr) * 136 + ks * 32 + quad * 8);
        acc[0][nt] = __builtin_amdgcn_mfma_f32_16x16x32_bf16(xa[0][ks], bfr, acc[0][nt], 0, 0, 0);
        acc[1][nt] = __builtin_amdgcn_mfma_f32_16x16x32_bf16(xa[1][ks], bfr, acc[1][nt], 0, 0, 0);
      }
    }

    if (w < 2) {
      unsigned short* outg = (w == 0) ? qg : kg;
#pragma unroll
      for (int mt = 0; mt < 2; ++mt) {
        const int rowbase = m0 + wave * 32 + mt * 16 + quad * 4;
#pragma unroll
        for (int nt = 0; nt < 8; ++nt) {
          float bb = bp[w][nt * 16 + mr];
#pragma unroll
          for (int r = 0; r < 4; ++r) {
            float t = fast_tanh(acc[mt][nt][r] + bb);
            outg[(size_t)(rowbase + r) * DD + nt * 16 + mr] = f2h(t);
          }
        }
      }
    } else {
      __syncthreads();
#pragma unroll
      for (int mt = 0; mt < 2; ++mt) {
        const int ib = wave * 32 + mt * 16 + quad * 4;
#pragma unroll
        for (int nt = 0; nt < 8; ++nt) {
          float bb = bp[2][nt * 16 + mr];
#pragma unroll
          for (int r = 0; r < 4; ++r) {
            float t = fast_tanh(acc[mt][nt][r] + bb);
            wlds[(nt * 16 + mr) * 136 + ib + r] = f2bf(t);
          }
        }
      }
      __syncthreads();
      const int h = tid >> 1, half = tid & 1;
      const unsigned short* src = wlds + h * 136 + half * 64;
      unsigned short* dst = vtg + (size_t)(batch * 128 + h) * NN + n0 + half * 64;
#pragma unroll
      for (int c = 0; c < 64; c += 8)
        *(uint4*)(dst + c) = *(const uint4*)(src + c);
    }
  }
}

// ---------------------------------------------------------------------------
// Kernel 2: flash-style masked attention.
// Block = 64 q-rows (4 waves x 16 rows), j-tiles of 64.
// K/VT staged via global_load_lds (async DMA, no VGPR round-trip -- R2's
// register staging was spilled to scratch: 525 MB/iter round-trip).
// DMA forces lane-contiguous LDS layout -> unpadded + XOR swizzle:
//   K   [64][128] f16,  slot g' = g ^ (row&15)  (16x 16B groups/row)
//   VT [128][ 64] bf16, slot g' = g ^ (row&7)   ( 8x 16B groups/row)
// -> frag-read banks ((g^mr)*4)%32 = 2-way = free. plds padded-72, aliases
// klds (disjoint phases). Mask bit-packed, applied at PV A-frag, prefetched
// one tile ahead. LDS 32768 B -> 4 blocks/CU.
// ---------------------------------------------------------------------------
__global__ __launch_bounds__(256, 2) void attn_kernel(
    const unsigned short* __restrict__ qg,
    const unsigned short* __restrict__ kg,
    const unsigned short* __restrict__ vtg,
    const int* __restrict__ mask,
    float* __restrict__ out)
{
  extern __shared__ unsigned short lds[];
  unsigned short* klds = lds;          // [64][128] f16 swizzled (S phase)
  unsigned short* plds = lds;          // [64][72]  bf16 (PV phase, alias)
  unsigned short* vlds = lds + 8192;   // [128][64] bf16 swizzled

  const int tid  = threadIdx.x;
  const int lane = tid & 63;
  const int wave = tid >> 6;
  const int quad = lane >> 4;
  const int mr   = lane & 15;

  const int bx    = blockIdx.x;
  const int batch = ((bx >> 7) << 3) | (bx & 7);   // same-batch blocks -> same XCD
  const int i0    = ((bx >> 3) & 15) * 64;

  const unsigned short* kgb = kg  + (size_t)batch * NN * DD;
  const unsigned short* vtb = vtg + (size_t)batch * DD * NN;
  const int* mrow = mask + ((size_t)batch << 20) + (size_t)(i0 + wave * 16 + mr) * NN;

  // Q A-frags (fp16): row = i0 + wave*16 + mr, k = ks*32 + quad*8 + e
  f16x8 qa[4];
#pragma unroll
  for (int ks = 0; ks < 4; ++ks)
    qa[ks] = *(const f16x8*)(qg +
        ((size_t)batch * NN + i0 + wave * 16 + mr) * DD + ks * 32 + quad * 8);

  f32x4 z = {0.f, 0.f, 0.f, 0.f};
  f32x4 o[8];
#pragma unroll
  for (int nt = 0; nt < 8; ++nt) o[nt] = z;
  float rowsum = 0.0f;

  // DMA slot decomposition (per 16B slot s = p*256 + tid):
  //   K : row = s>>4, g' = s&15, src group g = g' ^ (row&15)
  //   VT: row = s>>3, g' = s&7,  src group g = g' ^ (row&7)
  int krow[4], kgrp[4], vrow[4], vgrp[4];
#pragma unroll
  for (int p = 0; p < 4; ++p) {
    int s = p * 256 + tid;
    krow[p] = s >> 4; kgrp[p] = (s & 15) ^ (krow[p] & 15);
    vrow[p] = s >> 3; vgrp[p] = (s & 7)  ^ (vrow[p] & 7);
  }

  // mask prefetch for tile 0
  int4 mreg[4];
  mreg[0] = *(const int4*)(mrow + quad * 8);
  mreg[1] = *(const int4*)(mrow + quad * 8 + 4);
  mreg[2] = *(const int4*)(mrow + 32 + quad * 8);
  mreg[3] = *(const int4*)(mrow + 32 + quad * 8 + 4);

  for (int t = 0; t < 16; ++t) {
    const int j0 = t * 64;

    // pack mask bits for tile t; bit (ks2*8+e) = mask[row][j0 + ks2*32 + quad*8 + e]
    unsigned mb = 0;
#pragma unroll
    for (int i = 0; i < 4; ++i) {
      mb |= (unsigned)(mreg[i].x & 1) << (i * 4 + 0);
      mb |= (unsigned)(mreg[i].y & 1) << (i * 4 + 1);
      mb |= (unsigned)(mreg[i].z & 1) << (i * 4 + 2);
      mb |= (unsigned)(mreg[i].w & 1) << (i * 4 + 3);
    }

    __syncthreads();  // B1: prev PV reads of plds/vlds done
    // async DMA staging of K/VT tile t (16B/lane x 4 passes each)
#pragma unroll
    for (int p = 0; p < 4; ++p) {
      int s = p * 256 + tid;
      async_copy16(klds + s * 8, kgb + (size_t)(j0 + krow[p]) * DD + kgrp[p] * 8);
    }
#pragma unroll
    for (int p = 0; p < 4; ++p) {
      int s = p * 256 + tid;
      async_copy16(vlds + s * 8, vtb + (size_t)vrow[p] * NN + j0 + vgrp[p] * 8);
    }
    __syncthreads();  // B2: vmcnt(0) drain + barrier -> staging visible

    // mask prefetch for tile t+1 (drains at next iter's B2; long arrived)
    {
      const int j0n = ((t + 1) & 15) * 64;
      mreg[0] = *(const int4*)(mrow + j0n + quad * 8);
      mreg[1] = *(const int4*)(mrow + j0n + quad * 8 + 4);
      mreg[2] = *(const int4*)(mrow + j0n + 32 + quad * 8);
      mreg[3] = *(const int4*)(mrow + j0n + 32 + quad * 8 + 4);
    }

    // S = Q @ K^T (fp16 MFMA); per-wave tile 16 x 64; swizzled klds reads
    f32x4 s[4];
#pragma unroll
    for (int nt = 0; nt < 4; ++nt) s[nt] = z;
#pragma unroll
    for (int ks = 0; ks < 4; ++ks) {
#pragma unroll
      for (int nt = 0; nt < 4; ++nt) {
        f16x8 kb = *(const f16x8*)(klds + (nt * 16 + mr) * 128 + (((ks * 4 + quad) ^ mr) * 8));
        s[nt] = __builtin_amdgcn_mfma_f32_16x16x32_f16(qa[ks], kb, s[nt], 0, 0, 0);
      }
    }
    __syncthreads();  // B3: klds reads done, region becomes plds

    // P = exp(S) -> bf16 -> plds (unmasked; mask applied at A-frag read)
#pragma unroll
    for (int nt = 0; nt < 4; ++nt) {
#pragma unroll
      for (int r = 0; r < 4; ++r)
        plds[(wave * 16 + quad * 4 + r) * 72 + nt * 16 + mr] = f2bf(__expf(s[nt][r]));
    }
    __syncthreads();  // B4: P visible

    // O += P_masked @ V; row-sum accumulated in-lane from the same bf16 values
#pragma unroll
    for (int ks2 = 0; ks2 < 2; ++ks2) {
      bf16x8 pa = *(const bf16x8*)(plds + (wave * 16 + mr) * 72 + ks2 * 32 + quad * 8);
      bf16x8 pm;
#pragma unroll
      for (int e = 0; e < 8; ++e) {
        unsigned bit = (mb >> (ks2 * 8 + e)) & 1u;
        short pv = bit ? pa[e] : (short)0;
        pm[e] = pv;
        union { unsigned u; float f; } cv;
        cv.u = ((unsigned)(unsigned short)pv) << 16;
        rowsum += cv.f;
      }
#pragma unroll
      for (int nt = 0; nt < 8; ++nt) {
        bf16x8 vb = *(const bf16x8*)(vlds + (nt * 16 + mr) * 64 +
                                     (((ks2 * 4 + quad) ^ (mr & 7)) * 8));
        o[nt] = __builtin_amdgcn_mfma_f32_16x16x32_bf16(pm, vb, o[nt], 0, 0, 0);
      }
    }
  }

  // reduce row-sum across the 4 quads
  rowsum += __shfl_xor(rowsum, 16, 64);
  rowsum += __shfl_xor(rowsum, 32, 64);

  float* ob = out + ((size_t)batch * NN + i0) * DD;
#pragma unroll
  for (int r = 0; r < 4; ++r) {
    float rs  = __shfl(rowsum, quad * 4 + r, 64);  // rs for row wave*16+quad*4+r
    float inv = 1.0f / rs;
    float* orow = ob + (size_t)(wave * 16 + quad * 4 + r) * DD + mr;
#pragma unroll
    for (int nt = 0; nt < 8; ++nt)
      orow[nt * 16] = o[nt][r] * inv;
  }
}

// ---------------------------------------------------------------------------
extern "C" void kernel_launch(void* const* d_in, const int* in_sizes, int n_in,
                              void* d_out, int out_size, void* d_ws, size_t ws_size,
                              hipStream_t stream) {
  (void)in_sizes; (void)n_in; (void)out_size; (void)ws_size;
  const float* x  = (const float*)d_in[0];
  const int* mask = (const int*)d_in[1];
  const float* Wv = (const float*)d_in[2];
  const float* bv = (const float*)d_in[3];
  const float* Wk = (const float*)d_in[4];
  const float* bk = (const float*)d_in[5];
  const float* Wq = (const float*)d_in[6];
  const float* bq = (const float*)d_in[7];
  float* out = (float*)d_out;

  unsigned short* qg  = (unsigned short*)d_ws;          // fp16 [B][N][D]
  unsigned short* kg  = qg + (size_t)BB * NN * DD;      // fp16 [B][N][D]
  unsigned short* vtg = kg + (size_t)BB * NN * DD;      // bf16 [B][D][N]

  proj_kernel<<<512, 256, 0, stream>>>(x, Wq, bq, Wk, bk, Wv, bv, qg, kg, vtg);
  attn_kernel<<<1024, 256, 32768, stream>>>(qg, kg, vtg, mask, out);
}